// Round 2
// baseline (1138.554 us; speedup 1.0000x reference)
//
#include <hip/hip_runtime.h>
#include <math.h>

#define Tc 2048
#define Dc 1024
#define Hc 16
#define HDc 64
#define BT 4096                     // B*T
#define SCALE 0.35355339059327379f  // 64^-0.25

typedef _Float16 f16;
typedef __attribute__((ext_vector_type(4))) _Float16 f16x4;
typedef __attribute__((ext_vector_type(8))) _Float16 f16x8;
typedef __attribute__((ext_vector_type(4))) float f32x4;

__device__ __forceinline__ void gload16(const f16* g, f16* l)
{
    __builtin_amdgcn_global_load_lds(
        (const __attribute__((address_space(1))) void*)g,
        (__attribute__((address_space(3))) void*)l, 16, 0, 0);
}

// ---------------------------------------------------------------------------
// fused casts: 8 units of 1M floats (x in 4 chunks + 4 weights)
// ---------------------------------------------------------------------------
__global__ __launch_bounds__(256)
void cast_kernel(const float* __restrict__ x,
                 const float* __restrict__ Wq, const float* __restrict__ Wk,
                 const float* __restrict__ Wv, const float* __restrict__ Wo,
                 f16* __restrict__ xh,
                 f16* __restrict__ Wqh, f16* __restrict__ Wkh,
                 f16* __restrict__ Wvh, f16* __restrict__ Woh)
{
    const int u = blockIdx.y;
    const float* s; f16* d;
    if (u < 4) { s = x + (size_t)u * (1u << 20); d = xh + (size_t)u * (1u << 20); }
    else switch (u) {
        case 4:  s = Wq; d = Wqh; break;
        case 5:  s = Wk; d = Wkh; break;
        case 6:  s = Wv; d = Wvh; break;
        default: s = Wo; d = Woh; break;
    }
    int i = blockIdx.x * 256 + threadIdx.x;
    float4 v = ((const float4*)s)[i];
    f16x4 o = {(f16)v.x, (f16)v.y, (f16)v.z, (f16)v.w};
    ((f16x4*)d)[i] = o;
}

// ---------------------------------------------------------------------------
// m97-style GEMM core: 128x128 tile, BK=64, global_load_lds(16B) staging,
// T2 XOR swizzle (linear LDS dest, pre-swizzled global source, swizzled read).
// C(BT x Dc) = A * W^T.   Swizzle involution: byte-in-row ^= ((row&7)<<4).
// ---------------------------------------------------------------------------
#define GEMM_BODY(Aptr, Bptr)                                                        \
    __shared__ f16 As[128][64];                                                      \
    __shared__ f16 Bs[128][64];                                                      \
    const int tid = threadIdx.x;                                                     \
    const int w = tid >> 6, l = tid & 63;                                            \
    const int lr = l & 15, lq = l >> 4;                                              \
    const int wr = w >> 1, wc = w & 1;                                               \
    const int m0 = blockIdx.y * 128, n0 = blockIdx.x * 128;                          \
    const int srow8 = l >> 3, sslot = l & 7;                                         \
    f32x4 acc[4][4] = {};                                                            \
    for (int k0 = 0; k0 < Dc; k0 += 64) {                                            \
        __syncthreads();                                                             \
        _Pragma("unroll")                                                            \
        for (int c = 0; c < 4; c++) {                                                \
            int chunk = w * 4 + c;                                                   \
            int row = chunk * 8 + srow8;                                             \
            int col = (sslot ^ (row & 7)) * 8;                                       \
            gload16(&Aptr[(size_t)(m0 + row) * Dc + k0 + col],                       \
                    (f16*)((char*)&As[0][0] + chunk * 1024));                        \
            gload16(&Bptr[(size_t)(n0 + row) * Dc + k0 + col],                       \
                    (f16*)((char*)&Bs[0][0] + chunk * 1024));                        \
        }                                                                            \
        __syncthreads();                                                             \
        _Pragma("unroll")                                                            \
        for (int kk = 0; kk < 2; kk++) {                                             \
            f16x8 af[4], bf[4];                                                      \
            _Pragma("unroll")                                                        \
            for (int mi = 0; mi < 4; mi++) {                                         \
                int row = 64 * wr + 16 * mi + lr;                                    \
                int bo = (lq * 16 + kk * 64) ^ ((row & 7) << 4);                     \
                af[mi] = *(const f16x8*)((const char*)&As[0][0] + row * 128 + bo);   \
            }                                                                        \
            _Pragma("unroll")                                                        \
            for (int ni = 0; ni < 4; ni++) {                                         \
                int row = 64 * wc + 16 * ni + lr;                                    \
                int bo = (lq * 16 + kk * 64) ^ ((row & 7) << 4);                     \
                bf[ni] = *(const f16x8*)((const char*)&Bs[0][0] + row * 128 + bo);   \
            }                                                                        \
            _Pragma("unroll")                                                        \
            for (int mi = 0; mi < 4; mi++)                                           \
                _Pragma("unroll")                                                    \
                for (int ni = 0; ni < 4; ni++)                                       \
                    acc[mi][ni] = __builtin_amdgcn_mfma_f32_16x16x32_f16(            \
                        af[mi], bf[ni], acc[mi][ni], 0, 0, 0);                       \
        }                                                                            \
    }

// fused QKV projection + RoPE/scale epilogue, store f16 (B,H,T,HD)
__global__ __launch_bounds__(256)
void qkv_proj_kernel(const f16* __restrict__ xh,
                     const f16* __restrict__ Wqh, const f16* __restrict__ Wkh,
                     const f16* __restrict__ Wvh,
                     const float* __restrict__ bq, const float* __restrict__ bv,
                     f16* __restrict__ qh, f16* __restrict__ kh, f16* __restrict__ vh,
                     const float* __restrict__ cosp, const float* __restrict__ sinp)
{
    const int mode = blockIdx.z;
    const f16* W = (mode == 0) ? Wqh : (mode == 1 ? Wkh : Wvh);
    const float* bias = (mode == 0) ? bq : (mode == 2 ? bv : nullptr);
    f16* dst = (mode == 0) ? qh : (mode == 1 ? kh : vh);

    GEMM_BODY(xh, W)

    #pragma unroll
    for (int mi = 0; mi < 4; mi++) {
        #pragma unroll
        for (int ni = 0; ni < 4; ni++) {
            #pragma unroll
            for (int i = 0; i < 4; i++) {
                int gm = m0 + 64 * wr + 16 * mi + lq * 4 + i;
                int gn = n0 + 64 * wc + 16 * ni + lr;
                float v = acc[mi][ni][i];
                if (bias) v += bias[gn];
                int b = gm >> 11, t = gm & 2047;
                int h = gn >> 6, d = gn & 63;
                if (mode != 2) {
                    float pv = __shfl_xor(v, 1, 64);   // partner col gn^1
                    int p = d >> 1;
                    float c = cosp[t * 32 + p], s = sinp[t * 32 + p];
                    v = (d & 1) ? (pv * s + v * c) : (v * c - pv * s);
                    v *= SCALE;
                }
                dst[((size_t)(b * Hc + h) * Tc + t) * HDc + d] = (f16)v;
            }
        }
    }
}

// out projection: out(BT x Dc) = wvh * Wo^T + bo, fp32 store
__global__ __launch_bounds__(256)
void out_proj_kernel(const f16* __restrict__ A, const f16* __restrict__ W,
                     const float* __restrict__ bias, float* __restrict__ out)
{
    GEMM_BODY(A, W)

    #pragma unroll
    for (int mi = 0; mi < 4; mi++)
        #pragma unroll
        for (int ni = 0; ni < 4; ni++)
            #pragma unroll
            for (int i = 0; i < 4; i++) {
                int gm = m0 + 64 * wr + 16 * mi + lq * 4 + i;
                int gn = n0 + 64 * wc + 16 * ni + lr;
                out[(size_t)gm * Dc + gn] = acc[mi][ni][i] + bias[gn];
            }
}

// ---------------------------------------------------------------------------
// flash attention + S writeback.  Q-tile = 128 rows/block (wave owns 32),
// KV tile = 64: halves barriers / staging / softmax passes per S-element vs
// the 64-row version.  Register prefetch of next K/V tile hidden under
// compute (raw s_barrier + lgkm-only drain keeps prefetch in flight).
// qk stores are nontemporal (write-once stream; keep K/V/Q in L2).
// ---------------------------------------------------------------------------
__global__ __launch_bounds__(256)
void flash_kernel(const f16* __restrict__ qh, const f16* __restrict__ kh,
                  const f16* __restrict__ vh, f16* __restrict__ wvh,
                  float* __restrict__ qk)
{
    const int z = blockIdx.y;
    const int t0 = (gridDim.x - 1 - blockIdx.x) * 128;   // longest loops first
    const int tid = threadIdx.x;
    const int w = tid >> 6, l = tid & 63;
    const int lr = l & 15, lq = l >> 4;

    __shared__ f16 Qs[128][72];
    __shared__ f16 Ks[64][72];
    __shared__ f16 VsT[64][72];   // [d][s]
    __shared__ f16 Ps[128][72];   // [m][s]  (wave-private 32-row strips)

    const f16* Qg = qh + (size_t)z * Tc * HDc;
    const f16* Kg = kh + (size_t)z * Tc * HDc;
    const f16* Vg = vh + (size_t)z * Tc * HDc;
    float* C = qk + (size_t)z * Tc * Tc;

    {   // Q staging: 128 rows x 64, 2 threads/row
        int r = tid >> 1, c = (tid & 1) * 32;
        const f16* qp = &Qg[(size_t)(t0 + r) * HDc + c];
        *(f16x8*)&Qs[r][c]      = *(const f16x8*)qp;
        *(f16x8*)&Qs[r][c + 8]  = *(const f16x8*)(qp + 8);
        *(f16x8*)&Qs[r][c + 16] = *(const f16x8*)(qp + 16);
        *(f16x8*)&Qs[r][c + 24] = *(const f16x8*)(qp + 24);
    }

    // fill strictly-upper remainder: all 128 rows, cols [t0+128, Tc)
    {
        int r = t0 + (tid >> 1);             // 2 threads per row
        int n4 = (Tc - t0 - 128) >> 2;
        f32x4 mv = {-1e9f, -1e9f, -1e9f, -1e9f};
        f32x4* rowp = (f32x4*)(C + (size_t)r * Tc + t0 + 128);
        for (int c = (tid & 1); c < n4; c += 2)
            __builtin_nontemporal_store(mv, rowp + c);
    }

    // preload K/V tile 0 into registers
    const int kr = tid >> 2, kc = (tid & 3) * 16;
    const int vs = tid & 63, vd = (tid >> 6) * 16;
    f16x8 rk0 = *(const f16x8*)&Kg[(size_t)kr * HDc + kc];
    f16x8 rk1 = *(const f16x8*)&Kg[(size_t)kr * HDc + kc + 8];
    f16x8 rv0 = *(const f16x8*)&Vg[(size_t)vs * HDc + vd];
    f16x8 rv1 = *(const f16x8*)&Vg[(size_t)vs * HDc + vd + 8];

    f32x4 O[2][4] = {};
    float mrow[2][4], lrow[2][4];
    #pragma unroll
    for (int mi = 0; mi < 2; mi++)
        #pragma unroll
        for (int i = 0; i < 4; i++) { mrow[mi][i] = -1e30f; lrow[mi][i] = 0.f; }

    const int send = t0 + 64;                // last tile covers rows t0+64..t0+127
    for (int s0 = 0; s0 <= send; s0 += 64) {
        // barrier A: all waves done reading LDS of previous iteration
        asm volatile("" ::: "memory");
        __builtin_amdgcn_s_barrier();
        asm volatile("" ::: "memory");

        // write staged registers to LDS
        *(f16x8*)&Ks[kr][kc]     = rk0;
        *(f16x8*)&Ks[kr][kc + 8] = rk1;
        #pragma unroll
        for (int j = 0; j < 8; j++) {
            VsT[vd + j][vs]     = rv0[j];
            VsT[vd + 8 + j][vs] = rv1[j];
        }

        // prefetch next tile into registers (hidden under this iter's compute)
        if (s0 + 64 <= send) {
            const f16* kp = &Kg[(size_t)(s0 + 64 + kr) * HDc + kc];
            const f16* vp = &Vg[(size_t)(s0 + 64 + vs) * HDc + vd];
            rk0 = *(const f16x8*)kp;
            rk1 = *(const f16x8*)(kp + 8);
            rv0 = *(const f16x8*)vp;
            rv1 = *(const f16x8*)(vp + 8);
        }

        // barrier B: LDS writes visible (lgkm only — keep prefetch in flight)
        asm volatile("s_waitcnt lgkmcnt(0)" ::: "memory");
        __builtin_amdgcn_s_barrier();
        asm volatile("" ::: "memory");

        // S = Q K^T  (wave strip: q-rows 32w..32w+31, all 64 s)
        f32x4 S[2][4] = {};
        #pragma unroll
        for (int ks = 0; ks < 2; ks++) {
            f16x8 aq[2];
            #pragma unroll
            for (int mi = 0; mi < 2; mi++)
                aq[mi] = *(const f16x8*)&Qs[32 * w + 16 * mi + lr][lq * 8 + 32 * ks];
            #pragma unroll
            for (int ni = 0; ni < 4; ni++) {
                f16x8 bk = *(const f16x8*)&Ks[16 * ni + lr][lq * 8 + 32 * ks];
                #pragma unroll
                for (int mi = 0; mi < 2; mi++)
                    S[mi][ni] = __builtin_amdgcn_mfma_f32_16x16x32_f16(aq[mi], bk, S[mi][ni], 0, 0, 0);
            }
        }

        // causal mask where this tile touches/crosses the wave's diagonal
        if (s0 + 63 > t0 + 32 * w) {
            #pragma unroll
            for (int mi = 0; mi < 2; mi++)
                #pragma unroll
                for (int ni = 0; ni < 4; ni++)
                    #pragma unroll
                    for (int i = 0; i < 4; i++) {
                        int tg = t0 + 32 * w + 16 * mi + lq * 4 + i;
                        int sg = s0 + 16 * ni + lr;
                        if (sg > tg) S[mi][ni][i] = -1e9f;
                    }
        }

        // writeback S tile (output 1), post-mask pre-exp, nontemporal
        #pragma unroll
        for (int mi = 0; mi < 2; mi++)
            #pragma unroll
            for (int ni = 0; ni < 4; ni++)
                #pragma unroll
                for (int i = 0; i < 4; i++) {
                    int tg = t0 + 32 * w + 16 * mi + lq * 4 + i;
                    int sg = s0 + 16 * ni + lr;
                    __builtin_nontemporal_store(S[mi][ni][i], &C[(size_t)tg * Tc + sg]);
                }

        // online softmax per row (rows live across 16 lanes of a quad)
        #pragma unroll
        for (int mi = 0; mi < 2; mi++)
            #pragma unroll
            for (int i = 0; i < 4; i++) {
                float v = fmaxf(fmaxf(S[mi][0][i], S[mi][1][i]),
                                fmaxf(S[mi][2][i], S[mi][3][i]));
                v = fmaxf(v, __shfl_xor(v, 1, 64));
                v = fmaxf(v, __shfl_xor(v, 2, 64));
                v = fmaxf(v, __shfl_xor(v, 4, 64));
                v = fmaxf(v, __shfl_xor(v, 8, 64));
                float mnew = fmaxf(mrow[mi][i], v);
                float alpha = __expf(mrow[mi][i] - mnew);
                mrow[mi][i] = mnew;
                float rs = 0.f;
                #pragma unroll
                for (int ni = 0; ni < 4; ni++) {
                    float p = __expf(S[mi][ni][i] - mnew);
                    S[mi][ni][i] = p;
                    rs += p;
                }
                rs += __shfl_xor(rs, 1, 64);
                rs += __shfl_xor(rs, 2, 64);
                rs += __shfl_xor(rs, 4, 64);
                rs += __shfl_xor(rs, 8, 64);
                lrow[mi][i] = lrow[mi][i] * alpha + rs;
                #pragma unroll
                for (int ni = 0; ni < 4; ni++) O[mi][ni][i] *= alpha;
            }

        // P -> LDS (wave-private strip; no cross-wave hazard)
        #pragma unroll
        for (int mi = 0; mi < 2; mi++)
            #pragma unroll
            for (int ni = 0; ni < 4; ni++)
                #pragma unroll
                for (int i = 0; i < 4; i++)
                    Ps[32 * w + 16 * mi + lq * 4 + i][16 * ni + lr] = (f16)S[mi][ni][i];

        // O += P V
        #pragma unroll
        for (int ks = 0; ks < 2; ks++) {
            f16x8 ap[2];
            #pragma unroll
            for (int mi = 0; mi < 2; mi++)
                ap[mi] = *(const f16x8*)&Ps[32 * w + 16 * mi + lr][lq * 8 + 32 * ks];
            #pragma unroll
            for (int ni = 0; ni < 4; ni++) {
                f16x8 bv = *(const f16x8*)&VsT[16 * ni + lr][lq * 8 + 32 * ks];
                #pragma unroll
                for (int mi = 0; mi < 2; mi++)
                    O[mi][ni] = __builtin_amdgcn_mfma_f32_16x16x32_f16(ap[mi], bv, O[mi][ni], 0, 0, 0);
            }
        }
    }

    const int b = z >> 4, h = z & 15;
    #pragma unroll
    for (int mi = 0; mi < 2; mi++)
        #pragma unroll
        for (int ni = 0; ni < 4; ni++)
            #pragma unroll
            for (int i = 0; i < 4; i++) {
                int tg = t0 + 32 * w + 16 * mi + lq * 4 + i;
                int d = 16 * ni + lr;
                float o = O[mi][ni][i] / lrow[mi][i];
                wvh[((size_t)(b * Tc + tg)) * Dc + h * HDc + d] = (f16)o;
            }
}

// ---------------------------------------------------------------------------
extern "C" void kernel_launch(void* const* d_in, const int* in_sizes, int n_in,
                              void* d_out, int out_size, void* d_ws, size_t ws_size,
                              hipStream_t stream)
{
    const float* x    = (const float*)d_in[0];
    const float* cosp = (const float*)d_in[2];
    const float* sinp = (const float*)d_in[3];
    const float* Wq   = (const float*)d_in[4];
    const float* bq   = (const float*)d_in[5];
    const float* Wk   = (const float*)d_in[6];
    const float* Wv   = (const float*)d_in[7];
    const float* bv   = (const float*)d_in[8];
    const float* Wo   = (const float*)d_in[9];
    const float* bo   = (const float*)d_in[10];

    float* out = (float*)d_out;
    float* qk  = out + (size_t)BT * Dc;

    f16* ws  = (f16*)d_ws;
    f16* xh  = ws;
    f16* Wqh = xh  + (size_t)BT * Dc;
    f16* Wkh = Wqh + (size_t)Dc * Dc;
    f16* Wvh = Wkh + (size_t)Dc * Dc;
    f16* Woh = Wvh + (size_t)Dc * Dc;
    f16* qh  = Woh + (size_t)Dc * Dc;
    f16* kh  = qh  + (size_t)BT * Dc;
    f16* vh  = kh  + (size_t)BT * Dc;
    f16* wvh = vh  + (size_t)BT * Dc;

    dim3 blk(256);

    cast_kernel<<<dim3(1024, 8), blk, 0, stream>>>(
        x, Wq, Wk, Wv, Wo, xh, Wqh, Wkh, Wvh, Woh);

    qkv_proj_kernel<<<dim3(Dc / 128, BT / 128, 3), blk, 0, stream>>>(
        xh, Wqh, Wkh, Wvh, bq, bv, qh, kh, vh, cosp, sinp);

    flash_kernel<<<dim3(Tc / 128, 32), blk, 0, stream>>>(qh, kh, vh, wvh, qk);

    out_proj_kernel<<<dim3(Dc / 128, BT / 128), blk, 0, stream>>>(wvh, Woh, bo, out);
}

// Round 3
// 781.807 us; speedup vs baseline: 1.4563x; 1.4563x over previous
//
#include <hip/hip_runtime.h>
#include <math.h>

#define Tc 2048
#define Dc 1024
#define Hc 16
#define HDc 64
#define BT 4096                     // B*T
#define SCALE 0.35355339059327379f  // 64^-0.25

typedef _Float16 f16;
typedef __attribute__((ext_vector_type(4))) _Float16 f16x4;
typedef __attribute__((ext_vector_type(8))) _Float16 f16x8;
typedef __attribute__((ext_vector_type(4))) float f32x4;

__device__ __forceinline__ void gload16(const f16* g, f16* l)
{
    __builtin_amdgcn_global_load_lds(
        (const __attribute__((address_space(1))) void*)g,
        (__attribute__((address_space(3))) void*)l, 16, 0, 0);
}

// ---------------------------------------------------------------------------
// fused casts: 8 units of 1M floats (x in 4 chunks + 4 weights)
// ---------------------------------------------------------------------------
__global__ __launch_bounds__(256)
void cast_kernel(const float* __restrict__ x,
                 const float* __restrict__ Wq, const float* __restrict__ Wk,
                 const float* __restrict__ Wv, const float* __restrict__ Wo,
                 f16* __restrict__ xh,
                 f16* __restrict__ Wqh, f16* __restrict__ Wkh,
                 f16* __restrict__ Wvh, f16* __restrict__ Woh)
{
    const int u = blockIdx.y;
    const float* s; f16* d;
    if (u < 4) { s = x + (size_t)u * (1u << 20); d = xh + (size_t)u * (1u << 20); }
    else switch (u) {
        case 4:  s = Wq; d = Wqh; break;
        case 5:  s = Wk; d = Wkh; break;
        case 6:  s = Wv; d = Wvh; break;
        default: s = Wo; d = Woh; break;
    }
    int i = blockIdx.x * 256 + threadIdx.x;
    float4 v = ((const float4*)s)[i];
    f16x4 o = {(f16)v.x, (f16)v.y, (f16)v.z, (f16)v.w};
    ((f16x4*)d)[i] = o;
}

// ---------------------------------------------------------------------------
// m97-style GEMM core: 128x128 tile, BK=64, global_load_lds(16B) staging,
// T2 XOR swizzle (linear LDS dest, pre-swizzled global source, swizzled read).
// C(BT x Dc) = A * W^T.   Swizzle involution: byte-in-row ^= ((row&7)<<4).
// ---------------------------------------------------------------------------
#define GEMM_BODY(Aptr, Bptr)                                                        \
    __shared__ f16 As[128][64];                                                      \
    __shared__ f16 Bs[128][64];                                                      \
    const int tid = threadIdx.x;                                                     \
    const int w = tid >> 6, l = tid & 63;                                            \
    const int lr = l & 15, lq = l >> 4;                                              \
    const int wr = w >> 1, wc = w & 1;                                               \
    const int m0 = blockIdx.y * 128, n0 = blockIdx.x * 128;                          \
    const int srow8 = l >> 3, sslot = l & 7;                                         \
    f32x4 acc[4][4] = {};                                                            \
    for (int k0 = 0; k0 < Dc; k0 += 64) {                                            \
        __syncthreads();                                                             \
        _Pragma("unroll")                                                            \
        for (int c = 0; c < 4; c++) {                                                \
            int chunk = w * 4 + c;                                                   \
            int row = chunk * 8 + srow8;                                             \
            int col = (sslot ^ (row & 7)) * 8;                                       \
            gload16(&Aptr[(size_t)(m0 + row) * Dc + k0 + col],                       \
                    (f16*)((char*)&As[0][0] + chunk * 1024));                        \
            gload16(&Bptr[(size_t)(n0 + row) * Dc + k0 + col],                       \
                    (f16*)((char*)&Bs[0][0] + chunk * 1024));                        \
        }                                                                            \
        __syncthreads();                                                             \
        _Pragma("unroll")                                                            \
        for (int kk = 0; kk < 2; kk++) {                                             \
            f16x8 af[4], bf[4];                                                      \
            _Pragma("unroll")                                                        \
            for (int mi = 0; mi < 4; mi++) {                                         \
                int row = 64 * wr + 16 * mi + lr;                                    \
                int bo = (lq * 16 + kk * 64) ^ ((row & 7) << 4);                     \
                af[mi] = *(const f16x8*)((const char*)&As[0][0] + row * 128 + bo);   \
            }                                                                        \
            _Pragma("unroll")                                                        \
            for (int ni = 0; ni < 4; ni++) {                                         \
                int row = 64 * wc + 16 * ni + lr;                                    \
                int bo = (lq * 16 + kk * 64) ^ ((row & 7) << 4);                     \
                bf[ni] = *(const f16x8*)((const char*)&Bs[0][0] + row * 128 + bo);   \
            }                                                                        \
            _Pragma("unroll")                                                        \
            for (int mi = 0; mi < 4; mi++)                                           \
                _Pragma("unroll")                                                    \
                for (int ni = 0; ni < 4; ni++)                                       \
                    acc[mi][ni] = __builtin_amdgcn_mfma_f32_16x16x32_f16(            \
                        af[mi], bf[ni], acc[mi][ni], 0, 0, 0);                       \
        }                                                                            \
    }

// fused QKV projection + RoPE/scale epilogue, store f16 (B,H,T,HD)
__global__ __launch_bounds__(256)
void qkv_proj_kernel(const f16* __restrict__ xh,
                     const f16* __restrict__ Wqh, const f16* __restrict__ Wkh,
                     const f16* __restrict__ Wvh,
                     const float* __restrict__ bq, const float* __restrict__ bv,
                     f16* __restrict__ qh, f16* __restrict__ kh, f16* __restrict__ vh,
                     const float* __restrict__ cosp, const float* __restrict__ sinp)
{
    const int mode = blockIdx.z;
    const f16* W = (mode == 0) ? Wqh : (mode == 1 ? Wkh : Wvh);
    const float* bias = (mode == 0) ? bq : (mode == 2 ? bv : nullptr);
    f16* dst = (mode == 0) ? qh : (mode == 1 ? kh : vh);

    GEMM_BODY(xh, W)

    #pragma unroll
    for (int mi = 0; mi < 4; mi++) {
        #pragma unroll
        for (int ni = 0; ni < 4; ni++) {
            #pragma unroll
            for (int i = 0; i < 4; i++) {
                int gm = m0 + 64 * wr + 16 * mi + lq * 4 + i;
                int gn = n0 + 64 * wc + 16 * ni + lr;
                float v = acc[mi][ni][i];
                if (bias) v += bias[gn];
                int b = gm >> 11, t = gm & 2047;
                int h = gn >> 6, d = gn & 63;
                if (mode != 2) {
                    float pv = __shfl_xor(v, 1, 64);   // partner col gn^1
                    int p = d >> 1;
                    float c = cosp[t * 32 + p], s = sinp[t * 32 + p];
                    v = (d & 1) ? (pv * s + v * c) : (v * c - pv * s);
                    v *= SCALE;
                }
                dst[((size_t)(b * Hc + h) * Tc + t) * HDc + d] = (f16)v;
            }
        }
    }
}

// out projection: out(BT x Dc) = wvh * Wo^T + bo, fp32 store
__global__ __launch_bounds__(256)
void out_proj_kernel(const f16* __restrict__ A, const f16* __restrict__ W,
                     const float* __restrict__ bias, float* __restrict__ out)
{
    GEMM_BODY(A, W)

    #pragma unroll
    for (int mi = 0; mi < 4; mi++)
        #pragma unroll
        for (int ni = 0; ni < 4; ni++)
            #pragma unroll
            for (int i = 0; i < 4; i++) {
                int gm = m0 + 64 * wr + 16 * mi + lq * 4 + i;
                int gn = n0 + 64 * wc + 16 * ni + lr;
                out[(size_t)gm * Dc + gn] = acc[mi][ni][i] + bias[gn];
            }
}

// ---------------------------------------------------------------------------
// flash attention + S writeback.  64-row Q tile (r1 structure, measured good)
// + Q-hoist: Q fragments live in registers (each wave only needs its own 16
// rows), dropping the Qs LDS buffer -> 27.6 KB LDS -> 5 blocks/CU (20 waves).
// Register prefetch of next K/V tile hidden under compute (raw s_barrier +
// lgkm-only drain keeps the prefetch in flight).  Plain stores (L2 merges
// the 64B qk chunks).  s_setprio(1) around MFMA clusters (T5).
// ---------------------------------------------------------------------------
__global__ __launch_bounds__(256)
void flash_kernel(const f16* __restrict__ qh, const f16* __restrict__ kh,
                  const f16* __restrict__ vh, f16* __restrict__ wvh,
                  float* __restrict__ qk)
{
    const int z = blockIdx.y;
    const int t0 = (gridDim.x - 1 - blockIdx.x) * 64;   // longest flash loops first
    const int tid = threadIdx.x;
    const int w = tid >> 6, l = tid & 63;
    const int lr = l & 15, lq = l >> 4;

    __shared__ f16 Ks[64][72];
    __shared__ f16 VsT[64][72];   // [d][s]
    __shared__ f16 Ps[64][72];    // [m][s]

    const f16* Qg = qh + (size_t)z * Tc * HDc;
    const f16* Kg = kh + (size_t)z * Tc * HDc;
    const f16* Vg = vh + (size_t)z * Tc * HDc;
    float* C = qk + (size_t)z * Tc * Tc;

    // Q-hoist: this wave's A-fragments, straight from global (one-time)
    f16x8 aq[2];
    #pragma unroll
    for (int ks = 0; ks < 2; ks++)
        aq[ks] = *(const f16x8*)&Qg[(size_t)(t0 + 16 * w + lr) * HDc + lq * 8 + 32 * ks];

    // fill strictly-upper portion of this block's 64 rows: cols [t0+64, Tc)
    {
        int r = t0 + (tid >> 2);             // 4 threads per row
        int n4 = (Tc - t0 - 64) >> 2;        // float4s per row (multiple of 16)
        float4 mv; mv.x = mv.y = mv.z = mv.w = -1e9f;
        float4* rowp = (float4*)(C + (size_t)r * Tc + t0 + 64);
        for (int c = (tid & 3); c < n4; c += 4) rowp[c] = mv;
    }

    // preload K/V tile 0 into registers
    const int kr = tid >> 2, kc = (tid & 3) * 16;
    const int vs = tid & 63, vd = (tid >> 6) * 16;
    f16x8 rk0 = *(const f16x8*)&Kg[(size_t)kr * HDc + kc];
    f16x8 rk1 = *(const f16x8*)&Kg[(size_t)kr * HDc + kc + 8];
    f16x8 rv0 = *(const f16x8*)&Vg[(size_t)vs * HDc + vd];
    f16x8 rv1 = *(const f16x8*)&Vg[(size_t)vs * HDc + vd + 8];

    f32x4 O[4] = {};
    float mrow[4], lrow[4];
    #pragma unroll
    for (int i = 0; i < 4; i++) { mrow[i] = -1e30f; lrow[i] = 0.f; }

    for (int s0 = 0; s0 <= t0; s0 += 64) {
        // barrier A: all waves done reading LDS of previous iteration
        asm volatile("" ::: "memory");
        __builtin_amdgcn_s_barrier();
        asm volatile("" ::: "memory");

        // write staged registers to LDS
        *(f16x8*)&Ks[kr][kc]     = rk0;
        *(f16x8*)&Ks[kr][kc + 8] = rk1;
        #pragma unroll
        for (int j = 0; j < 8; j++) {
            VsT[vd + j][vs]     = rv0[j];
            VsT[vd + 8 + j][vs] = rv1[j];
        }

        // prefetch next tile into registers (hidden under this iter's compute)
        if (s0 + 64 <= t0) {
            const f16* kp = &Kg[(size_t)(s0 + 64 + kr) * HDc + kc];
            const f16* vp = &Vg[(size_t)(s0 + 64 + vs) * HDc + vd];
            rk0 = *(const f16x8*)kp;
            rk1 = *(const f16x8*)(kp + 8);
            rv0 = *(const f16x8*)vp;
            rv1 = *(const f16x8*)(vp + 8);
        }

        // barrier B: LDS writes visible (lgkm only — keep prefetch in flight)
        asm volatile("s_waitcnt lgkmcnt(0)" ::: "memory");
        __builtin_amdgcn_s_barrier();
        asm volatile("" ::: "memory");

        // S = Q K^T  (wave strip: q-rows 16w..16w+15, all 64 s)
        f32x4 S[4] = {};
        __builtin_amdgcn_s_setprio(1);
        #pragma unroll
        for (int ks = 0; ks < 2; ks++) {
            #pragma unroll
            for (int ni = 0; ni < 4; ni++) {
                f16x8 bk = *(const f16x8*)&Ks[16 * ni + lr][lq * 8 + 32 * ks];
                S[ni] = __builtin_amdgcn_mfma_f32_16x16x32_f16(aq[ks], bk, S[ni], 0, 0, 0);
            }
        }
        __builtin_amdgcn_s_setprio(0);

        if (s0 == t0) {   // diagonal tile: causal mask
            #pragma unroll
            for (int ni = 0; ni < 4; ni++)
                #pragma unroll
                for (int i = 0; i < 4; i++) {
                    int tg = t0 + 16 * w + lq * 4 + i;
                    int sg = s0 + 16 * ni + lr;
                    if (sg > tg) S[ni][i] = -1e9f;
                }
        }

        // writeback S tile (output 1), post-mask pre-exp
        #pragma unroll
        for (int ni = 0; ni < 4; ni++)
            #pragma unroll
            for (int i = 0; i < 4; i++) {
                int tg = t0 + 16 * w + lq * 4 + i;
                int sg = s0 + 16 * ni + lr;
                C[(size_t)tg * Tc + sg] = S[ni][i];
            }

        // online softmax per row (rows live across 16 lanes of a quad)
        #pragma unroll
        for (int i = 0; i < 4; i++) {
            float v = fmaxf(fmaxf(S[0][i], S[1][i]), fmaxf(S[2][i], S[3][i]));
            v = fmaxf(v, __shfl_xor(v, 1, 64));
            v = fmaxf(v, __shfl_xor(v, 2, 64));
            v = fmaxf(v, __shfl_xor(v, 4, 64));
            v = fmaxf(v, __shfl_xor(v, 8, 64));
            float mnew = fmaxf(mrow[i], v);
            float alpha = __expf(mrow[i] - mnew);
            mrow[i] = mnew;
            float rs = 0.f;
            #pragma unroll
            for (int ni = 0; ni < 4; ni++) {
                float p = __expf(S[ni][i] - mnew);
                S[ni][i] = p;
                rs += p;
            }
            rs += __shfl_xor(rs, 1, 64);
            rs += __shfl_xor(rs, 2, 64);
            rs += __shfl_xor(rs, 4, 64);
            rs += __shfl_xor(rs, 8, 64);
            lrow[i] = lrow[i] * alpha + rs;
            #pragma unroll
            for (int ni = 0; ni < 4; ni++) O[ni][i] *= alpha;
        }

        // P -> LDS (wave-private strip; no cross-wave hazard)
        #pragma unroll
        for (int ni = 0; ni < 4; ni++)
            #pragma unroll
            for (int i = 0; i < 4; i++)
                Ps[16 * w + lq * 4 + i][16 * ni + lr] = (f16)S[ni][i];

        // O += P V
        __builtin_amdgcn_s_setprio(1);
        #pragma unroll
        for (int ks = 0; ks < 2; ks++) {
            f16x8 ap = *(const f16x8*)&Ps[16 * w + lr][lq * 8 + 32 * ks];
            #pragma unroll
            for (int ni = 0; ni < 4; ni++) {
                f16x8 bv = *(const f16x8*)&VsT[16 * ni + lr][lq * 8 + 32 * ks];
                O[ni] = __builtin_amdgcn_mfma_f32_16x16x32_f16(ap, bv, O[ni], 0, 0, 0);
            }
        }
        __builtin_amdgcn_s_setprio(0);
    }

    const int b = z >> 4, h = z & 15;
    #pragma unroll
    for (int ni = 0; ni < 4; ni++)
        #pragma unroll
        for (int i = 0; i < 4; i++) {
            int tg = t0 + 16 * w + lq * 4 + i;
            int d = 16 * ni + lr;
            float o = O[ni][i] / lrow[i];
            wvh[((size_t)(b * Tc + tg)) * Dc + h * HDc + d] = (f16)o;
        }
}

// ---------------------------------------------------------------------------
extern "C" void kernel_launch(void* const* d_in, const int* in_sizes, int n_in,
                              void* d_out, int out_size, void* d_ws, size_t ws_size,
                              hipStream_t stream)
{
    const float* x    = (const float*)d_in[0];
    const float* cosp = (const float*)d_in[2];
    const float* sinp = (const float*)d_in[3];
    const float* Wq   = (const float*)d_in[4];
    const float* bq   = (const float*)d_in[5];
    const float* Wk   = (const float*)d_in[6];
    const float* Wv   = (const float*)d_in[7];
    const float* bv   = (const float*)d_in[8];
    const float* Wo   = (const float*)d_in[9];
    const float* bo   = (const float*)d_in[10];

    float* out = (float*)d_out;
    float* qk  = out + (size_t)BT * Dc;

    f16* ws  = (f16*)d_ws;
    f16* xh  = ws;
    f16* Wqh = xh  + (size_t)BT * Dc;
    f16* Wkh = Wqh + (size_t)Dc * Dc;
    f16* Wvh = Wkh + (size_t)Dc * Dc;
    f16* Woh = Wvh + (size_t)Dc * Dc;
    f16* qh  = Woh + (size_t)Dc * Dc;
    f16* kh  = qh  + (size_t)BT * Dc;
    f16* vh  = kh  + (size_t)BT * Dc;
    f16* wvh = vh  + (size_t)BT * Dc;

    dim3 blk(256);

    cast_kernel<<<dim3(1024, 8), blk, 0, stream>>>(
        x, Wq, Wk, Wv, Wo, xh, Wqh, Wkh, Wvh, Woh);

    qkv_proj_kernel<<<dim3(Dc / 128, BT / 128, 3), blk, 0, stream>>>(
        xh, Wqh, Wkh, Wvh, bq, bv, qh, kh, vh, cosp, sinp);

    flash_kernel<<<dim3(Tc / 64, 32), blk, 0, stream>>>(qh, kh, vh, wvh, qk);

    out_proj_kernel<<<dim3(Dc / 128, BT / 128), blk, 0, stream>>>(wvh, Woh, bo, out);
}

// Round 4
// 767.416 us; speedup vs baseline: 1.4836x; 1.0188x over previous
//
#include <hip/hip_runtime.h>
#include <math.h>

#define Tc 2048
#define Dc 1024
#define Hc 16
#define HDc 64
#define BT 4096                     // B*T
#define SCALE 0.35355339059327379f  // 64^-0.25

typedef _Float16 f16;
typedef __attribute__((ext_vector_type(4))) _Float16 f16x4;
typedef __attribute__((ext_vector_type(8))) _Float16 f16x8;
typedef __attribute__((ext_vector_type(4))) float f32x4;

__device__ __forceinline__ void gload16(const f16* g, f16* l)
{
    __builtin_amdgcn_global_load_lds(
        (const __attribute__((address_space(1))) void*)g,
        (__attribute__((address_space(3))) void*)l, 16, 0, 0);
}

// ---------------------------------------------------------------------------
// fused casts: 8 units of 1M floats (x in 4 chunks + 4 weights)
// ---------------------------------------------------------------------------
__global__ __launch_bounds__(256)
void cast_kernel(const float* __restrict__ x,
                 const float* __restrict__ Wq, const float* __restrict__ Wk,
                 const float* __restrict__ Wv, const float* __restrict__ Wo,
                 f16* __restrict__ xh,
                 f16* __restrict__ Wqh, f16* __restrict__ Wkh,
                 f16* __restrict__ Wvh, f16* __restrict__ Woh)
{
    const int u = blockIdx.y;
    const float* s; f16* d;
    if (u < 4) { s = x + (size_t)u * (1u << 20); d = xh + (size_t)u * (1u << 20); }
    else switch (u) {
        case 4:  s = Wq; d = Wqh; break;
        case 5:  s = Wk; d = Wkh; break;
        case 6:  s = Wv; d = Wvh; break;
        default: s = Wo; d = Woh; break;
    }
    int i = blockIdx.x * 256 + threadIdx.x;
    float4 v = ((const float4*)s)[i];
    f16x4 o = {(f16)v.x, (f16)v.y, (f16)v.z, (f16)v.w};
    ((f16x4*)d)[i] = o;
}

// ---------------------------------------------------------------------------
// m97-style GEMM core: 128x128 tile, BK=64, global_load_lds(16B) staging,
// T2 XOR swizzle (linear LDS dest, pre-swizzled global source, swizzled read).
// C(BT x Dc) = A * W^T.   Swizzle involution: byte-in-row ^= ((row&7)<<4).
// ---------------------------------------------------------------------------
#define GEMM_BODY(Aptr, Bptr)                                                        \
    __shared__ f16 As[128][64];                                                      \
    __shared__ f16 Bs[128][64];                                                      \
    const int tid = threadIdx.x;                                                     \
    const int w = tid >> 6, l = tid & 63;                                            \
    const int lr = l & 15, lq = l >> 4;                                              \
    const int wr = w >> 1, wc = w & 1;                                               \
    const int m0 = blockIdx.y * 128, n0 = blockIdx.x * 128;                          \
    const int srow8 = l >> 3, sslot = l & 7;                                         \
    f32x4 acc[4][4] = {};                                                            \
    for (int k0 = 0; k0 < Dc; k0 += 64) {                                            \
        __syncthreads();                                                             \
        _Pragma("unroll")                                                            \
        for (int c = 0; c < 4; c++) {                                                \
            int chunk = w * 4 + c;                                                   \
            int row = chunk * 8 + srow8;                                             \
            int col = (sslot ^ (row & 7)) * 8;                                       \
            gload16(&Aptr[(size_t)(m0 + row) * Dc + k0 + col],                       \
                    (f16*)((char*)&As[0][0] + chunk * 1024));                        \
            gload16(&Bptr[(size_t)(n0 + row) * Dc + k0 + col],                       \
                    (f16*)((char*)&Bs[0][0] + chunk * 1024));                        \
        }                                                                            \
        __syncthreads();                                                             \
        _Pragma("unroll")                                                            \
        for (int kk = 0; kk < 2; kk++) {                                             \
            f16x8 af[4], bf[4];                                                      \
            _Pragma("unroll")                                                        \
            for (int mi = 0; mi < 4; mi++) {                                         \
                int row = 64 * wr + 16 * mi + lr;                                    \
                int bo = (lq * 16 + kk * 64) ^ ((row & 7) << 4);                     \
                af[mi] = *(const f16x8*)((const char*)&As[0][0] + row * 128 + bo);   \
            }                                                                        \
            _Pragma("unroll")                                                        \
            for (int ni = 0; ni < 4; ni++) {                                         \
                int row = 64 * wc + 16 * ni + lr;                                    \
                int bo = (lq * 16 + kk * 64) ^ ((row & 7) << 4);                     \
                bf[ni] = *(const f16x8*)((const char*)&Bs[0][0] + row * 128 + bo);   \
            }                                                                        \
            _Pragma("unroll")                                                        \
            for (int mi = 0; mi < 4; mi++)                                           \
                _Pragma("unroll")                                                    \
                for (int ni = 0; ni < 4; ni++)                                       \
                    acc[mi][ni] = __builtin_amdgcn_mfma_f32_16x16x32_f16(            \
                        af[mi], bf[ni], acc[mi][ni], 0, 0, 0);                       \
        }                                                                            \
    }

// fused QKV projection + RoPE/scale epilogue, store f16 (B,H,T,HD)
__global__ __launch_bounds__(256)
void qkv_proj_kernel(const f16* __restrict__ xh,
                     const f16* __restrict__ Wqh, const f16* __restrict__ Wkh,
                     const f16* __restrict__ Wvh,
                     const float* __restrict__ bq, const float* __restrict__ bv,
                     f16* __restrict__ qh, f16* __restrict__ kh, f16* __restrict__ vh,
                     const float* __restrict__ cosp, const float* __restrict__ sinp)
{
    const int mode = blockIdx.z;
    const f16* W = (mode == 0) ? Wqh : (mode == 1 ? Wkh : Wvh);
    const float* bias = (mode == 0) ? bq : (mode == 2 ? bv : nullptr);
    f16* dst = (mode == 0) ? qh : (mode == 1 ? kh : vh);

    GEMM_BODY(xh, W)

    #pragma unroll
    for (int mi = 0; mi < 4; mi++) {
        #pragma unroll
        for (int ni = 0; ni < 4; ni++) {
            #pragma unroll
            for (int i = 0; i < 4; i++) {
                int gm = m0 + 64 * wr + 16 * mi + lq * 4 + i;
                int gn = n0 + 64 * wc + 16 * ni + lr;
                float v = acc[mi][ni][i];
                if (bias) v += bias[gn];
                int b = gm >> 11, t = gm & 2047;
                int h = gn >> 6, d = gn & 63;
                if (mode != 2) {
                    float pv = __shfl_xor(v, 1, 64);   // partner col gn^1
                    int p = d >> 1;
                    float c = cosp[t * 32 + p], s = sinp[t * 32 + p];
                    v = (d & 1) ? (pv * s + v * c) : (v * c - pv * s);
                    v *= SCALE;
                }
                dst[((size_t)(b * Hc + h) * Tc + t) * HDc + d] = (f16)v;
            }
        }
    }
}

// out projection: out(BT x Dc) = wvh * Wo^T + bo, fp32 store
__global__ __launch_bounds__(256)
void out_proj_kernel(const f16* __restrict__ A, const f16* __restrict__ W,
                     const float* __restrict__ bias, float* __restrict__ out)
{
    GEMM_BODY(A, W)

    #pragma unroll
    for (int mi = 0; mi < 4; mi++)
        #pragma unroll
        for (int ni = 0; ni < 4; ni++)
            #pragma unroll
            for (int i = 0; i < 4; i++) {
                int gm = m0 + 64 * wr + 16 * mi + lq * 4 + i;
                int gn = n0 + 64 * wc + 16 * ni + lr;
                out[(size_t)gm * Dc + gn] = acc[mi][ni][i] + bias[gn];
            }
}

// ---------------------------------------------------------------------------
// flash attention + S writeback.  Occupancy-first build:
//   LDS 25.0 KB  (Ks linear [64][64] via gload_lds + GEMM XOR swizzle;
//                 VsT/Ps pad 68)  -> 6 blocks/CU by LDS
//   __launch_bounds__(256,6)     -> VGPR capped ~84 -> 6 waves/SIMD
//   no reg-prefetch (worthless at fixed occupancy; 24-wave TLP hides latency)
//   Q-hoist in registers; plain __syncthreads (drains vmcnt for gload_lds).
// ---------------------------------------------------------------------------
__global__ __launch_bounds__(256, 6)
void flash_kernel(const f16* __restrict__ qh, const f16* __restrict__ kh,
                  const f16* __restrict__ vh, f16* __restrict__ wvh,
                  float* __restrict__ qk)
{
    const int z = blockIdx.y;
    const int t0 = (gridDim.x - 1 - blockIdx.x) * 64;   // longest flash loops first
    const int tid = threadIdx.x;
    const int w = tid >> 6, l = tid & 63;
    const int lr = l & 15, lq = l >> 4;

    __shared__ f16 Ks[64][64];    // linear, contents XOR-swizzled (as GEMM tiles)
    __shared__ f16 VsT[64][68];   // [d][s]
    __shared__ f16 Ps[64][68];    // [m][s]

    const f16* Qg = qh + (size_t)z * Tc * HDc;
    const f16* Kg = kh + (size_t)z * Tc * HDc;
    const f16* Vg = vh + (size_t)z * Tc * HDc;
    float* C = qk + (size_t)z * Tc * Tc;

    // Q-hoist: this wave's A-fragments, straight from global (one-time)
    f16x8 aq[2];
    #pragma unroll
    for (int ks = 0; ks < 2; ks++)
        aq[ks] = *(const f16x8*)&Qg[(size_t)(t0 + 16 * w + lr) * HDc + lq * 8 + 32 * ks];

    // fill strictly-upper portion of this block's 64 rows: cols [t0+64, Tc)
    {
        int r = t0 + (tid >> 2);             // 4 threads per row
        int n4 = (Tc - t0 - 64) >> 2;        // float4s per row (multiple of 16)
        float4 mv; mv.x = mv.y = mv.z = mv.w = -1e9f;
        float4* rowp = (float4*)(C + (size_t)r * Tc + t0 + 64);
        for (int c = (tid & 3); c < n4; c += 4) rowp[c] = mv;
    }

    f32x4 O[4] = {};
    float mrow[4], lrow[4];
    #pragma unroll
    for (int i = 0; i < 4; i++) { mrow[i] = -1e30f; lrow[i] = 0.f; }

    const int srow8 = l >> 3, sslot = l & 7;

    for (int s0 = 0; s0 <= t0; s0 += 64) {
        __syncthreads();   // prior-iteration LDS reads done

        // stage K: gload_lds(16B), linear LDS dest, pre-swizzled global source
        #pragma unroll
        for (int c = 0; c < 2; c++) {
            int chunk = w * 2 + c;
            int row = chunk * 8 + srow8;
            int col = (sslot ^ (row & 7)) * 8;
            gload16(&Kg[(size_t)(s0 + row) * HDc + col],
                    (f16*)((char*)&Ks[0][0] + chunk * 1024));
        }
        // stage V transposed via registers
        {
            const f16* vp = &Vg[(size_t)(s0 + l) * HDc + w * 16];
            f16x8 v0 = *(const f16x8*)vp;
            f16x8 v1 = *(const f16x8*)(vp + 8);
            #pragma unroll
            for (int j = 0; j < 8; j++) {
                VsT[w * 16 + j][l]     = v0[j];
                VsT[w * 16 + 8 + j][l] = v1[j];
            }
        }
        __syncthreads();   // drains vmcnt (gload_lds) + lgkm (ds_writes)

        // S = Q K^T  (wave strip: q-rows 16w..16w+15, all 64 s)
        f32x4 S[4] = {};
        __builtin_amdgcn_s_setprio(1);
        #pragma unroll
        for (int ks = 0; ks < 2; ks++) {
            #pragma unroll
            for (int ni = 0; ni < 4; ni++) {
                int krow = 16 * ni + lr;
                int bo = (lq * 16 + ks * 64) ^ ((krow & 7) << 4);
                f16x8 bk = *(const f16x8*)((const char*)&Ks[0][0] + krow * 128 + bo);
                S[ni] = __builtin_amdgcn_mfma_f32_16x16x32_f16(aq[ks], bk, S[ni], 0, 0, 0);
            }
        }
        __builtin_amdgcn_s_setprio(0);

        if (s0 == t0) {   // diagonal tile: causal mask
            #pragma unroll
            for (int ni = 0; ni < 4; ni++)
                #pragma unroll
                for (int i = 0; i < 4; i++) {
                    int tg = t0 + 16 * w + lq * 4 + i;
                    int sg = s0 + 16 * ni + lr;
                    if (sg > tg) S[ni][i] = -1e9f;
                }
        }

        // writeback S tile (output 1), post-mask pre-exp
        #pragma unroll
        for (int ni = 0; ni < 4; ni++)
            #pragma unroll
            for (int i = 0; i < 4; i++) {
                int tg = t0 + 16 * w + lq * 4 + i;
                int sg = s0 + 16 * ni + lr;
                C[(size_t)tg * Tc + sg] = S[ni][i];
            }

        // online softmax per row (rows live across 16 lanes of a quad)
        #pragma unroll
        for (int i = 0; i < 4; i++) {
            float v = fmaxf(fmaxf(S[0][i], S[1][i]), fmaxf(S[2][i], S[3][i]));
            v = fmaxf(v, __shfl_xor(v, 1, 64));
            v = fmaxf(v, __shfl_xor(v, 2, 64));
            v = fmaxf(v, __shfl_xor(v, 4, 64));
            v = fmaxf(v, __shfl_xor(v, 8, 64));
            float mnew = fmaxf(mrow[i], v);
            float alpha = __expf(mrow[i] - mnew);
            mrow[i] = mnew;
            float rs = 0.f;
            #pragma unroll
            for (int ni = 0; ni < 4; ni++) {
                float p = __expf(S[ni][i] - mnew);
                S[ni][i] = p;
                rs += p;
            }
            rs += __shfl_xor(rs, 1, 64);
            rs += __shfl_xor(rs, 2, 64);
            rs += __shfl_xor(rs, 4, 64);
            rs += __shfl_xor(rs, 8, 64);
            lrow[i] = lrow[i] * alpha + rs;
            #pragma unroll
            for (int ni = 0; ni < 4; ni++) O[ni][i] *= alpha;
        }

        // P -> LDS (wave-private strip; no cross-wave hazard)
        #pragma unroll
        for (int ni = 0; ni < 4; ni++)
            #pragma unroll
            for (int i = 0; i < 4; i++)
                Ps[16 * w + lq * 4 + i][16 * ni + lr] = (f16)S[ni][i];

        // O += P V
        __builtin_amdgcn_s_setprio(1);
        #pragma unroll
        for (int ks = 0; ks < 2; ks++) {
            f16x8 ap = *(const f16x8*)&Ps[16 * w + lr][lq * 8 + 32 * ks];
            #pragma unroll
            for (int ni = 0; ni < 4; ni++) {
                f16x8 bv = *(const f16x8*)&VsT[16 * ni + lr][lq * 8 + 32 * ks];
                O[ni] = __builtin_amdgcn_mfma_f32_16x16x32_f16(ap, bv, O[ni], 0, 0, 0);
            }
        }
        __builtin_amdgcn_s_setprio(0);
    }

    const int b = z >> 4, h = z & 15;
    #pragma unroll
    for (int ni = 0; ni < 4; ni++)
        #pragma unroll
        for (int i = 0; i < 4; i++) {
            int tg = t0 + 16 * w + lq * 4 + i;
            int d = 16 * ni + lr;
            float o = O[ni][i] / lrow[i];
            wvh[((size_t)(b * Tc + tg)) * Dc + h * HDc + d] = (f16)o;
        }
}

// ---------------------------------------------------------------------------
extern "C" void kernel_launch(void* const* d_in, const int* in_sizes, int n_in,
                              void* d_out, int out_size, void* d_ws, size_t ws_size,
                              hipStream_t stream)
{
    const float* x    = (const float*)d_in[0];
    const float* cosp = (const float*)d_in[2];
    const float* sinp = (const float*)d_in[3];
    const float* Wq   = (const float*)d_in[4];
    const float* bq   = (const float*)d_in[5];
    const float* Wk   = (const float*)d_in[6];
    const float* Wv   = (const float*)d_in[7];
    const float* bv   = (const float*)d_in[8];
    const float* Wo   = (const float*)d_in[9];
    const float* bo   = (const float*)d_in[10];

    float* out = (float*)d_out;
    float* qk  = out + (size_t)BT * Dc;

    f16* ws  = (f16*)d_ws;
    f16* xh  = ws;
    f16* Wqh = xh  + (size_t)BT * Dc;
    f16* Wkh = Wqh + (size_t)Dc * Dc;
    f16* Wvh = Wkh + (size_t)Dc * Dc;
    f16* Woh = Wvh + (size_t)Dc * Dc;
    f16* qh  = Woh + (size_t)Dc * Dc;
    f16* kh  = qh  + (size_t)BT * Dc;
    f16* vh  = kh  + (size_t)BT * Dc;
    f16* wvh = vh  + (size_t)BT * Dc;

    dim3 blk(256);

    cast_kernel<<<dim3(1024, 8), blk, 0, stream>>>(
        x, Wq, Wk, Wv, Wo, xh, Wqh, Wkh, Wvh, Woh);

    qkv_proj_kernel<<<dim3(Dc / 128, BT / 128, 3), blk, 0, stream>>>(
        xh, Wqh, Wkh, Wvh, bq, bv, qh, kh, vh, cosp, sinp);

    flash_kernel<<<dim3(Tc / 64, 32), blk, 0, stream>>>(qh, kh, vh, wvh, qk);

    out_proj_kernel<<<dim3(Dc / 128, BT / 128), blk, 0, stream>>>(wvh, Woh, bo, out);
}

// Round 5
// 726.664 us; speedup vs baseline: 1.5668x; 1.0561x over previous
//
#include <hip/hip_runtime.h>
#include <math.h>

#define Tc 2048
#define Dc 1024
#define Hc 16
#define HDc 64
#define BT 4096                     // B*T
#define SCALE 0.35355339059327379f  // 64^-0.25

typedef _Float16 f16;
typedef __attribute__((ext_vector_type(4))) _Float16 f16x4;
typedef __attribute__((ext_vector_type(8))) _Float16 f16x8;
typedef __attribute__((ext_vector_type(4))) float f32x4;

__device__ __forceinline__ void gload16(const f16* g, f16* l)
{
    __builtin_amdgcn_global_load_lds(
        (const __attribute__((address_space(1))) void*)g,
        (__attribute__((address_space(3))) void*)l, 16, 0, 0);
}

// 16-lane allreduce step via DPP (VALU pipe, no LDS): quad_perm xor1/xor2
// then row_ror:4 / row_ror:8 complete the 16-lane reduction.
template <int C>
__device__ __forceinline__ float fdpp(float x)
{
    return __int_as_float(__builtin_amdgcn_update_dpp(
        0, __float_as_int(x), C, 0xF, 0xF, true));
}
__device__ __forceinline__ float rmax16(float v)
{
    v = fmaxf(v, fdpp<0xB1>(v));    // quad_perm [1,0,3,2]  (xor 1)
    v = fmaxf(v, fdpp<0x4E>(v));    // quad_perm [2,3,0,1]  (xor 2)
    v = fmaxf(v, fdpp<0x124>(v));   // row_ror:4
    v = fmaxf(v, fdpp<0x128>(v));   // row_ror:8
    return v;
}
__device__ __forceinline__ float rsum16(float v)
{
    v += fdpp<0xB1>(v);
    v += fdpp<0x4E>(v);
    v += fdpp<0x124>(v);
    v += fdpp<0x128>(v);
    return v;
}

// ---------------------------------------------------------------------------
// fused casts: 8 units of 1M floats (x in 4 chunks + 4 weights)
// ---------------------------------------------------------------------------
__global__ __launch_bounds__(256)
void cast_kernel(const float* __restrict__ x,
                 const float* __restrict__ Wq, const float* __restrict__ Wk,
                 const float* __restrict__ Wv, const float* __restrict__ Wo,
                 f16* __restrict__ xh,
                 f16* __restrict__ Wqh, f16* __restrict__ Wkh,
                 f16* __restrict__ Wvh, f16* __restrict__ Woh)
{
    const int u = blockIdx.y;
    const float* s; f16* d;
    if (u < 4) { s = x + (size_t)u * (1u << 20); d = xh + (size_t)u * (1u << 20); }
    else switch (u) {
        case 4:  s = Wq; d = Wqh; break;
        case 5:  s = Wk; d = Wkh; break;
        case 6:  s = Wv; d = Wvh; break;
        default: s = Wo; d = Woh; break;
    }
    int i = blockIdx.x * 256 + threadIdx.x;
    float4 v = ((const float4*)s)[i];
    f16x4 o = {(f16)v.x, (f16)v.y, (f16)v.z, (f16)v.w};
    ((f16x4*)d)[i] = o;
}

// ---------------------------------------------------------------------------
// 2-phase double-buffered GEMM core: 128x64 tile, BK=64, gload_lds(16B),
// XOR swizzle (linear LDS dest, pre-swizzled global source, swizzled read).
// STAGE(next) is issued BEFORE the compute phase so the load flight time
// overlaps MFMA; a single __syncthreads per K-step (drains vmcnt+lgkm).
// Wave w computes rows 32w..32w+31 x all 64 cols; acc[2][4].
// ---------------------------------------------------------------------------
#define GEMM_BODY(Aptr, Bptr)                                                        \
    __shared__ f16 As[2][128 * 64];                                                  \
    __shared__ f16 Bs[2][64 * 64];                                                   \
    const int tid = threadIdx.x;                                                     \
    const int w = tid >> 6, l = tid & 63;                                            \
    const int lr = l & 15, lq = l >> 4;                                              \
    const int m0 = blockIdx.y * 128, n0 = blockIdx.x * 64;                           \
    const int srow8 = l >> 3, sslot = l & 7;                                         \
    f32x4 acc[2][4] = {};                                                            \
    auto STAGE = [&](int b, int k0) {                                                \
        _Pragma("unroll")                                                            \
        for (int c = 0; c < 6; c++) {                                                \
            int chunk = w * 6 + c;                                                   \
            if (chunk < 16) {                                                        \
                int row = chunk * 8 + srow8;                                         \
                int col = (sslot ^ (row & 7)) * 8;                                   \
                gload16(&Aptr[(size_t)(m0 + row) * Dc + k0 + col],                   \
                        &As[b][chunk * 512]);                                        \
            } else {                                                                 \
                int row = (chunk - 16) * 8 + srow8;                                  \
                int col = (sslot ^ (row & 7)) * 8;                                   \
                gload16(&Bptr[(size_t)(n0 + row) * Dc + k0 + col],                   \
                        &Bs[b][(chunk - 16) * 512]);                                 \
            }                                                                        \
        }                                                                            \
    };                                                                               \
    STAGE(0, 0);                                                                     \
    __syncthreads();                                                                 \
    int cur = 0;                                                                     \
    for (int k0 = 0; k0 < Dc; k0 += 64) {                                            \
        if (k0 + 64 < Dc) STAGE(cur ^ 1, k0 + 64);                                   \
        _Pragma("unroll")                                                            \
        for (int kk = 0; kk < 2; kk++) {                                             \
            f16x8 af[2], bf[4];                                                      \
            _Pragma("unroll")                                                        \
            for (int mi = 0; mi < 2; mi++) {                                         \
                int row = 32 * w + 16 * mi + lr;                                     \
                int bo = (lq * 16 + kk * 64) ^ ((row & 7) << 4);                     \
                af[mi] = *(const f16x8*)((const char*)&As[cur][0] + row * 128 + bo); \
            }                                                                        \
            _Pragma("unroll")                                                        \
            for (int ni = 0; ni < 4; ni++) {                                         \
                int row = 16 * ni + lr;                                              \
                int bo = (lq * 16 + kk * 64) ^ ((row & 7) << 4);                     \
                bf[ni] = *(const f16x8*)((const char*)&Bs[cur][0] + row * 128 + bo); \
            }                                                                        \
            _Pragma("unroll")                                                        \
            for (int mi = 0; mi < 2; mi++)                                           \
                _Pragma("unroll")                                                    \
                for (int ni = 0; ni < 4; ni++)                                       \
                    acc[mi][ni] = __builtin_amdgcn_mfma_f32_16x16x32_f16(            \
                        af[mi], bf[ni], acc[mi][ni], 0, 0, 0);                       \
        }                                                                            \
        __syncthreads();                                                             \
        cur ^= 1;                                                                    \
    }

// fused QKV projection + RoPE/scale epilogue, store f16 (B,H,T,HD)
__global__ __launch_bounds__(256, 3)
void qkv_proj_kernel(const f16* __restrict__ xh,
                     const f16* __restrict__ Wqh, const f16* __restrict__ Wkh,
                     const f16* __restrict__ Wvh,
                     const float* __restrict__ bq, const float* __restrict__ bv,
                     f16* __restrict__ qh, f16* __restrict__ kh, f16* __restrict__ vh,
                     const float* __restrict__ cosp, const float* __restrict__ sinp)
{
    const int mode = blockIdx.z;
    const f16* W = (mode == 0) ? Wqh : (mode == 1 ? Wkh : Wvh);
    const float* bias = (mode == 0) ? bq : (mode == 2 ? bv : nullptr);
    f16* dst = (mode == 0) ? qh : (mode == 1 ? kh : vh);

    GEMM_BODY(xh, W)

    #pragma unroll
    for (int mi = 0; mi < 2; mi++) {
        #pragma unroll
        for (int ni = 0; ni < 4; ni++) {
            #pragma unroll
            for (int i = 0; i < 4; i++) {
                int gm = m0 + 32 * w + 16 * mi + lq * 4 + i;
                int gn = n0 + 16 * ni + lr;
                float v = acc[mi][ni][i];
                if (bias) v += bias[gn];
                int b = gm >> 11, t = gm & 2047;
                int h = gn >> 6, d = gn & 63;
                if (mode != 2) {
                    float pv = __shfl_xor(v, 1, 64);   // partner col gn^1
                    int p = d >> 1;
                    float c = cosp[t * 32 + p], s = sinp[t * 32 + p];
                    v = (d & 1) ? (pv * s + v * c) : (v * c - pv * s);
                    v *= SCALE;
                }
                dst[((size_t)(b * Hc + h) * Tc + t) * HDc + d] = (f16)v;
            }
        }
    }
}

// out projection: out(BT x Dc) = wvh * Wo^T + bo, fp32 store
__global__ __launch_bounds__(256, 3)
void out_proj_kernel(const f16* __restrict__ A, const f16* __restrict__ W,
                     const float* __restrict__ bias, float* __restrict__ out)
{
    GEMM_BODY(A, W)

    #pragma unroll
    for (int mi = 0; mi < 2; mi++)
        #pragma unroll
        for (int ni = 0; ni < 4; ni++)
            #pragma unroll
            for (int i = 0; i < 4; i++) {
                int gm = m0 + 32 * w + 16 * mi + lq * 4 + i;
                int gn = n0 + 16 * ni + lr;
                out[(size_t)gm * Dc + gn] = acc[mi][ni][i] + bias[gn];
            }
}

// ---------------------------------------------------------------------------
// flash attention + S writeback (r4 structure, 25 KB LDS, launch_bounds(256,6)):
//  - DPP-based 16-lane reductions (VALU pipe) instead of __shfl_xor
//  - upper-triangle fill moved AFTER the main loop (its stores no longer sit
//    in the vmem queue ahead of the first K/V load + barrier drain)
// ---------------------------------------------------------------------------
__global__ __launch_bounds__(256, 6)
void flash_kernel(const f16* __restrict__ qh, const f16* __restrict__ kh,
                  const f16* __restrict__ vh, f16* __restrict__ wvh,
                  float* __restrict__ qk)
{
    const int z = blockIdx.y;
    const int t0 = (gridDim.x - 1 - blockIdx.x) * 64;   // longest flash loops first
    const int tid = threadIdx.x;
    const int w = tid >> 6, l = tid & 63;
    const int lr = l & 15, lq = l >> 4;

    __shared__ f16 Ks[64][64];    // linear, contents XOR-swizzled (as GEMM tiles)
    __shared__ f16 VsT[64][68];   // [d][s]
    __shared__ f16 Ps[64][68];    // [m][s]

    const f16* Qg = qh + (size_t)z * Tc * HDc;
    const f16* Kg = kh + (size_t)z * Tc * HDc;
    const f16* Vg = vh + (size_t)z * Tc * HDc;
    float* C = qk + (size_t)z * Tc * Tc;

    // Q-hoist: this wave's A-fragments, straight from global (one-time)
    f16x8 aq[2];
    #pragma unroll
    for (int ks = 0; ks < 2; ks++)
        aq[ks] = *(const f16x8*)&Qg[(size_t)(t0 + 16 * w + lr) * HDc + lq * 8 + 32 * ks];

    f32x4 O[4] = {};
    float mrow[4], lrow[4];
    #pragma unroll
    for (int i = 0; i < 4; i++) { mrow[i] = -1e30f; lrow[i] = 0.f; }

    const int srow8 = l >> 3, sslot = l & 7;

    for (int s0 = 0; s0 <= t0; s0 += 64) {
        __syncthreads();   // prior-iteration LDS reads done

        // stage K: gload_lds(16B), linear LDS dest, pre-swizzled global source
        #pragma unroll
        for (int c = 0; c < 2; c++) {
            int chunk = w * 2 + c;
            int row = chunk * 8 + srow8;
            int col = (sslot ^ (row & 7)) * 8;
            gload16(&Kg[(size_t)(s0 + row) * HDc + col],
                    (f16*)((char*)&Ks[0][0] + chunk * 1024));
        }
        // stage V transposed via registers
        {
            const f16* vp = &Vg[(size_t)(s0 + l) * HDc + w * 16];
            f16x8 v0 = *(const f16x8*)vp;
            f16x8 v1 = *(const f16x8*)(vp + 8);
            #pragma unroll
            for (int j = 0; j < 8; j++) {
                VsT[w * 16 + j][l]     = v0[j];
                VsT[w * 16 + 8 + j][l] = v1[j];
            }
        }
        __syncthreads();   // drains vmcnt (gload_lds) + lgkm (ds_writes)

        // S = Q K^T  (wave strip: q-rows 16w..16w+15, all 64 s)
        f32x4 S[4] = {};
        __builtin_amdgcn_s_setprio(1);
        #pragma unroll
        for (int ks = 0; ks < 2; ks++) {
            #pragma unroll
            for (int ni = 0; ni < 4; ni++) {
                int krow = 16 * ni + lr;
                int bo = (lq * 16 + ks * 64) ^ ((krow & 7) << 4);
                f16x8 bk = *(const f16x8*)((const char*)&Ks[0][0] + krow * 128 + bo);
                S[ni] = __builtin_amdgcn_mfma_f32_16x16x32_f16(aq[ks], bk, S[ni], 0, 0, 0);
            }
        }
        __builtin_amdgcn_s_setprio(0);

        if (s0 == t0) {   // diagonal tile: causal mask
            #pragma unroll
            for (int ni = 0; ni < 4; ni++)
                #pragma unroll
                for (int i = 0; i < 4; i++) {
                    int tg = t0 + 16 * w + lq * 4 + i;
                    int sg = s0 + 16 * ni + lr;
                    if (sg > tg) S[ni][i] = -1e9f;
                }
        }

        // writeback S tile (output 1), post-mask pre-exp
        #pragma unroll
        for (int ni = 0; ni < 4; ni++)
            #pragma unroll
            for (int i = 0; i < 4; i++) {
                int tg = t0 + 16 * w + lq * 4 + i;
                int sg = s0 + 16 * ni + lr;
                C[(size_t)tg * Tc + sg] = S[ni][i];
            }

        // online softmax per row (rows live across 16 lanes of a quad)
        #pragma unroll
        for (int i = 0; i < 4; i++) {
            float v = fmaxf(fmaxf(S[0][i], S[1][i]), fmaxf(S[2][i], S[3][i]));
            v = rmax16(v);
            float mnew = fmaxf(mrow[i], v);
            float alpha = __expf(mrow[i] - mnew);
            mrow[i] = mnew;
            float rs = 0.f;
            #pragma unroll
            for (int ni = 0; ni < 4; ni++) {
                float p = __expf(S[ni][i] - mnew);
                S[ni][i] = p;
                rs += p;
            }
            rs = rsum16(rs);
            lrow[i] = lrow[i] * alpha + rs;
            #pragma unroll
            for (int ni = 0; ni < 4; ni++) O[ni][i] *= alpha;
        }

        // P -> LDS (wave-private strip; no cross-wave hazard)
        #pragma unroll
        for (int ni = 0; ni < 4; ni++)
            #pragma unroll
            for (int i = 0; i < 4; i++)
                Ps[16 * w + lq * 4 + i][16 * ni + lr] = (f16)S[ni][i];

        // O += P V
        __builtin_amdgcn_s_setprio(1);
        #pragma unroll
        for (int ks = 0; ks < 2; ks++) {
            f16x8 ap = *(const f16x8*)&Ps[16 * w + lr][lq * 8 + 32 * ks];
            #pragma unroll
            for (int ni = 0; ni < 4; ni++) {
                f16x8 bv = *(const f16x8*)&VsT[16 * ni + lr][lq * 8 + 32 * ks];
                O[ni] = __builtin_amdgcn_mfma_f32_16x16x32_f16(ap, bv, O[ni], 0, 0, 0);
            }
        }
        __builtin_amdgcn_s_setprio(0);
    }

    const int b = z >> 4, h = z & 15;
    #pragma unroll
    for (int ni = 0; ni < 4; ni++)
        #pragma unroll
        for (int i = 0; i < 4; i++) {
            int tg = t0 + 16 * w + lq * 4 + i;
            int d = 16 * ni + lr;
            float o = O[ni][i] / lrow[i];
            wvh[((size_t)(b * Tc + tg)) * Dc + h * HDc + d] = (f16)o;
        }

    // fill strictly-upper portion of this block's 64 rows: cols [t0+64, Tc)
    // (moved after the loop: keeps the vmem queue clear for K/V staging)
    {
        int r = t0 + (tid >> 2);             // 4 threads per row
        int n4 = (Tc - t0 - 64) >> 2;        // float4s per row (multiple of 16)
        float4 mv; mv.x = mv.y = mv.z = mv.w = -1e9f;
        float4* rowp = (float4*)(C + (size_t)r * Tc + t0 + 64);
        for (int c = (tid & 3); c < n4; c += 4) rowp[c] = mv;
    }
}

// ---------------------------------------------------------------------------
extern "C" void kernel_launch(void* const* d_in, const int* in_sizes, int n_in,
                              void* d_out, int out_size, void* d_ws, size_t ws_size,
                              hipStream_t stream)
{
    const float* x    = (const float*)d_in[0];
    const float* cosp = (const float*)d_in[2];
    const float* sinp = (const float*)d_in[3];
    const float* Wq   = (const float*)d_in[4];
    const float* bq   = (const float*)d_in[5];
    const float* Wk   = (const float*)d_in[6];
    const float* Wv   = (const float*)d_in[7];
    const float* bv   = (const float*)d_in[8];
    const float* Wo   = (const float*)d_in[9];
    const float* bo   = (const float*)d_in[10];

    float* out = (float*)d_out;
    float* qk  = out + (size_t)BT * Dc;

    f16* ws  = (f16*)d_ws;
    f16* xh  = ws;
    f16* Wqh = xh  + (size_t)BT * Dc;
    f16* Wkh = Wqh + (size_t)Dc * Dc;
    f16* Wvh = Wkh + (size_t)Dc * Dc;
    f16* Woh = Wvh + (size_t)Dc * Dc;
    f16* qh  = Woh + (size_t)Dc * Dc;
    f16* kh  = qh  + (size_t)BT * Dc;
    f16* vh  = kh  + (size_t)BT * Dc;
    f16* wvh = vh  + (size_t)BT * Dc;

    dim3 blk(256);

    cast_kernel<<<dim3(1024, 8), blk, 0, stream>>>(
        x, Wq, Wk, Wv, Wo, xh, Wqh, Wkh, Wvh, Woh);

    qkv_proj_kernel<<<dim3(Dc / 64, BT / 128, 3), blk, 0, stream>>>(
        xh, Wqh, Wkh, Wvh, bq, bv, qh, kh, vh, cosp, sinp);

    flash_kernel<<<dim3(Tc / 64, 32), blk, 0, stream>>>(qh, kh, vh, wvh, qk);

    out_proj_kernel<<<dim3(Dc / 64, BT / 128), blk, 0, stream>>>(wvh, Woh, bo, out);
}